// Round 5
// baseline (69.843 us; speedup 1.0000x reference)
//
#include <hip/hip_runtime.h>
#include <hip/hip_bf16.h>

// RSA layer, B=64, U=W=128. Grid 8x64 (512 blocks, 2/CU for latency overlap).
// Only i=W-1 output row needed; hj-term and bias cancel in softmax over j.
// sim-hi matmul + dot matvec via bf16 MFMA 16x16x32; softmax in-register with
// small cross-wave LDS exchanges (3 barriers total).
constexpr int Bx = 64, Ux = 128, Wx = 128;
constexpr int NS = 8;           // v-chunks per batch
constexpr int VC = 16;          // v columns per block
constexpr int LDST = 136;       // st_s stride (bf16): 272B = 17*16B (b128-aligned rows)
constexpr int LDWT = 136;

typedef __attribute__((ext_vector_type(8))) short s16x8;   // MFMA A/B frag
typedef __attribute__((ext_vector_type(4))) float fx4;     // MFMA C/D frag

static __device__ __forceinline__ short f2b(float x) {     // f32 -> bf16 RNE
  union { float f; unsigned u; } c; c.f = x;
  unsigned r = c.u + 0x7fffu + ((c.u >> 16) & 1u);
  return (short)(r >> 16);
}
static __device__ __forceinline__ float b2f(short s) {     // bf16 -> f32 exact
  union { unsigned u; float f; } c; c.u = ((unsigned)(unsigned short)s) << 16;
  return c.f;
}

__global__ __launch_bounds__(256) void rsa_kernel(const float* __restrict__ input,
                                                  const float* __restrict__ state,
                                                  const float* __restrict__ w,
                                                  float* __restrict__ out) {
  __shared__ __align__(16) short st_s[Wx][LDST];  // [j][k]=state[j][k], [j][128]=input[j]
  __shared__ __align__(16) short wst[VC][LDWT];   // [v][k]=w_hi[k-1][vb+v], [v][0]=0
  __shared__ float colmax[4][VC], colsum[4][VC], ppart[4][VC];
  __shared__ float w127_s[VC], wdot_s[VC];
  __shared__ float dpart[2];

  const int t = threadIdx.x;
  const int s = blockIdx.x, b = blockIdx.y;
  const int vb = s * VC;
  const float* stb = state + (size_t)b * Ux * Wx;
  const float* inb = input + (size_t)b * Ux;

  // ---- stage state -> bf16 (float4 loads, aligned b128 LDS writes)
#pragma unroll
  for (int i = 0; i < 4; ++i) {
    int g = i * 4096 + t * 16;          // flat f32 index, 16-aligned
    int j = g >> 7, k = g & 127;
    const float4* src = reinterpret_cast<const float4*>(stb + g);
    float4 x0 = src[0], x1 = src[1], x2 = src[2], x3 = src[3];
    s16x8 p0 = { f2b(x0.x), f2b(x0.y), f2b(x0.z), f2b(x0.w),
                 f2b(x1.x), f2b(x1.y), f2b(x1.z), f2b(x1.w) };
    s16x8 p1 = { f2b(x2.x), f2b(x2.y), f2b(x2.z), f2b(x2.w),
                 f2b(x3.x), f2b(x3.y), f2b(x3.z), f2b(x3.w) };
    *reinterpret_cast<s16x8*>(&st_s[j][k])     = p0;
    *reinterpret_cast<s16x8*>(&st_s[j][k + 8]) = p1;
  }
  if (t < Wx) st_s[t][128] = f2b(inb[t]);
  // ---- stage w_hi chunk shifted: wst[v][r+1] = w_hi[r][vb+v], r=0..126
  for (int idx = t; idx < 127 * VC; idx += 256) {
    int r = idx >> 4, v = idx & (VC - 1);
    wst[v][r + 1] = f2b(w[r * Ux + vb + v]);
  }
  if (t < VC) { wst[t][0] = 0; w127_s[t] = w[127 * Ux + vb + t]; }
  else if (t < 2 * VC) wdot_s[t - VC] = w[2 * Ux * Ux + vb + (t - VC)];
  // ---- exact fp32 dot[127] = ||flip_127||^2 (waves 0,1)
  if (t < Wx) {
    float x = (t < Wx - 1) ? stb[127 * Wx + t + 1] : inb[127];
    float p = x * x;
#pragma unroll
    for (int off = 32; off; off >>= 1) p += __shfl_down(p, off);
    if ((t & 63) == 0) dpart[t >> 6] = p;
  }
  __syncthreads();

  // ---- MFMA: wave wv owns j rows wv*32..wv*32+31; all 16 v's of this chunk.
  // A/B frag: row/col = l&15, k-contig 8 at (l>>4)*8; D: col=l&15, row=(l>>4)*4+r
  const int wv = t >> 6, l = t & 63, lc = l & 15, lg = l >> 4;
  fx4 aH[2] = {};
  fx4 aD[2] = {};
#pragma unroll
  for (int kt = 0; kt < 4; ++kt) {
    const int ko = kt * 32 + lg * 8;
    s16x8 bd = *reinterpret_cast<const s16x8*>(&st_s[127][ko]);   // broadcast row 127
    s16x8 b0 = *reinterpret_cast<const s16x8*>(&wst[lc][ko]);
#pragma unroll
    for (int jl = 0; jl < 2; ++jl) {
      s16x8 a = *reinterpret_cast<const s16x8*>(&st_s[wv * 32 + jl * 16 + lc][ko]);
      aH[jl] = __builtin_amdgcn_mfma_f32_16x16x32_bf16(a, b0, aH[jl], 0, 0, 0);
      aD[jl] = __builtin_amdgcn_mfma_f32_16x16x32_bf16(a, bd, aD[jl], 0, 0, 0);
    }
  }

  // ---- epilogue in registers: shift corrections + dot*w_dot + input*w_hi[127]
  const float in127  = b2f(st_s[127][128]);
  const float st0127 = b2f(st_s[127][0]);
  const float d127   = dpart[0] + dpart[1];
  const float wd0 = wdot_s[lc];
  const float w70 = w127_s[lc];
  float sim[2][4];
#pragma unroll
  for (int jl = 0; jl < 2; ++jl) {
#pragma unroll
    for (int r = 0; r < 4; ++r) {
      const int row = wv * 32 + jl * 16 + lg * 4 + r;
      float st0 = b2f(st_s[row][0]);
      float inr = b2f(st_s[row][128]);
      float dotv = aD[jl][r] - st0 * st0127 + inr * in127;
      if (row == Wx - 1) dotv = d127;                 // exact fp32 diagonal
      sim[jl][r] = aH[jl][r] + dotv * wd0 + inr * w70;
    }
  }

  // ---- softmax over j: per-wave in-register reduce + [4][16] cross-wave LDS
  float m0 = -3.4e38f;
#pragma unroll
  for (int jl = 0; jl < 2; ++jl)
#pragma unroll
    for (int r = 0; r < 4; ++r) m0 = fmaxf(m0, sim[jl][r]);
  m0 = fmaxf(m0, __shfl_xor(m0, 16)); m0 = fmaxf(m0, __shfl_xor(m0, 32));
  if (l < VC) colmax[wv][l] = m0;
  __syncthreads();
  const float M0 = fmaxf(fmaxf(colmax[0][lc], colmax[1][lc]),
                         fmaxf(colmax[2][lc], colmax[3][lc]));
  float s0 = 0.f, p0 = 0.f;
#pragma unroll
  for (int jl = 0; jl < 2; ++jl)
#pragma unroll
    for (int r = 0; r < 4; ++r) {
      const int row = wv * 32 + jl * 16 + lg * 4 + r;
      float e0 = __expf(sim[jl][r] - M0);
      s0 += e0;
      p0 = fmaf(b2f(st_s[row][vb + lc + 1]), e0, p0);   // flip[row][vb+lc] (col127 -> [128]=input)
    }
  s0 += __shfl_xor(s0, 16); s0 += __shfl_xor(s0, 32);
  p0 += __shfl_xor(p0, 16); p0 += __shfl_xor(p0, 32);
  if (l < VC) { colsum[wv][l] = s0; ppart[wv][l] = p0; }
  __syncthreads();

  if (wv == 0 && l < VC) {
    float S = colsum[0][l] + colsum[1][l] + colsum[2][l] + colsum[3][l];
    float P = ppart[0][l] + ppart[1][l] + ppart[2][l] + ppart[3][l];
    out[(size_t)b * Ux + vb + l] = P / S;
  }
}

extern "C" void kernel_launch(void* const* d_in, const int* in_sizes, int n_in,
                              void* d_out, int out_size, void* d_ws, size_t ws_size,
                              hipStream_t stream) {
  const float* input = (const float*)d_in[0];
  const float* state = (const float*)d_in[1];
  const float* w     = (const float*)d_in[2];
  // d_in[3] (bias) not needed: cancels in softmax over j.
  float* out = (float*)d_out;
  dim3 grid(NS, Bx);
  rsa_kernel<<<grid, dim3(256), 0, stream>>>(input, state, w, out);
}

// Round 6
// 66.084 us; speedup vs baseline: 1.0569x; 1.0569x over previous
//
#include <hip/hip_runtime.h>
#include <hip/hip_bf16.h>

// RSA layer, B=64, U=W=128. Grid 4x64 (256 blocks = 1/CU), 512 threads (8 waves).
// Only i=W-1 output row needed; hj-term and bias cancel in softmax over j.
// sim-hi matmul + dot matvec via bf16 MFMA 16x16x32; softmax in-register with
// small cross-wave LDS exchanges (3 barriers total).
constexpr int Bx = 64, Ux = 128, Wx = 128;
constexpr int NS = 4;           // v-chunks per batch
constexpr int VC = 32;          // v columns per block
constexpr int LDST = 136;       // st_s stride (bf16): 272B = 17*16B (b128-aligned rows)
constexpr int LDWT = 136;

typedef __attribute__((ext_vector_type(8))) short s16x8;   // MFMA A/B frag
typedef __attribute__((ext_vector_type(4))) float fx4;     // MFMA C/D frag

static __device__ __forceinline__ short f2b(float x) {     // f32 -> bf16 RNE
  union { float f; unsigned u; } c; c.f = x;
  unsigned r = c.u + 0x7fffu + ((c.u >> 16) & 1u);
  return (short)(r >> 16);
}
static __device__ __forceinline__ float b2f(short s) {     // bf16 -> f32 exact
  union { unsigned u; float f; } c; c.u = ((unsigned)(unsigned short)s) << 16;
  return c.f;
}

__global__ __launch_bounds__(512) void rsa_kernel(const float* __restrict__ input,
                                                  const float* __restrict__ state,
                                                  const float* __restrict__ w,
                                                  float* __restrict__ out) {
  __shared__ __align__(16) short st_s[Wx][LDST];  // [j][k]=state[j][k], [j][128]=input[j]
  __shared__ __align__(16) short wst[VC][LDWT];   // [v][k]=w_hi[k-1][vb+v], [v][0]=0
  __shared__ float colmax[8][VC], colsum[8][VC], ppart[8][VC];
  __shared__ float w127_s[VC], wdot_s[VC];
  __shared__ float dpart[2];

  const int t = threadIdx.x;
  const int s = blockIdx.x, b = blockIdx.y;
  const int vb = s * VC;
  const float* stb = state + (size_t)b * Ux * Wx;
  const float* inb = input + (size_t)b * Ux;

  // ---- stage state -> bf16 (float4 loads, aligned b128 LDS writes)
#pragma unroll
  for (int i = 0; i < 2; ++i) {
    int g = i * 8192 + t * 16;          // flat f32 index, 16-aligned
    int j = g >> 7, k = g & 127;
    const float4* src = reinterpret_cast<const float4*>(stb + g);
    float4 x0 = src[0], x1 = src[1], x2 = src[2], x3 = src[3];
    s16x8 p0 = { f2b(x0.x), f2b(x0.y), f2b(x0.z), f2b(x0.w),
                 f2b(x1.x), f2b(x1.y), f2b(x1.z), f2b(x1.w) };
    s16x8 p1 = { f2b(x2.x), f2b(x2.y), f2b(x2.z), f2b(x2.w),
                 f2b(x3.x), f2b(x3.y), f2b(x3.z), f2b(x3.w) };
    *reinterpret_cast<s16x8*>(&st_s[j][k])     = p0;
    *reinterpret_cast<s16x8*>(&st_s[j][k + 8]) = p1;
  }
  if (t < Wx) st_s[t][128] = f2b(inb[t]);
  // ---- stage w_hi chunk shifted: wst[v][r+1] = w_hi[r][vb+v], r=0..126
  for (int idx = t; idx < 127 * VC; idx += 512) {
    int r = idx >> 5, v = idx & (VC - 1);
    wst[v][r + 1] = f2b(w[r * Ux + vb + v]);
  }
  if (t < VC) { wst[t][0] = 0; w127_s[t] = w[127 * Ux + vb + t]; }
  else if (t < 2 * VC) wdot_s[t - VC] = w[2 * Ux * Ux + vb + (t - VC)];
  // ---- exact fp32 dot[127] = ||flip_127||^2 (waves 0,1)
  if (t < Wx) {
    float x = (t < Wx - 1) ? stb[127 * Wx + t + 1] : inb[127];
    float p = x * x;
#pragma unroll
    for (int off = 32; off; off >>= 1) p += __shfl_down(p, off);
    if ((t & 63) == 0) dpart[t >> 6] = p;
  }
  __syncthreads();

  // ---- MFMA: wave wv owns j-tile rows wv*16..wv*16+15; 2 v-tiles + dot matvec.
  // A/B frag: row/col = l&15, k-contig 8 at (l>>4)*8; D: col=l&15, row=(l>>4)*4+r
  const int wv = t >> 6, l = t & 63, lc = l & 15, lg = l >> 4;
  fx4 aH0 = {}, aH1 = {}, aD = {};
#pragma unroll
  for (int kt = 0; kt < 4; ++kt) {
    const int ko = kt * 32 + lg * 8;
    s16x8 bd = *reinterpret_cast<const s16x8*>(&st_s[127][ko]);   // broadcast row 127
    s16x8 b0 = *reinterpret_cast<const s16x8*>(&wst[lc][ko]);
    s16x8 b1 = *reinterpret_cast<const s16x8*>(&wst[lc + 16][ko]);
    s16x8 a  = *reinterpret_cast<const s16x8*>(&st_s[wv * 16 + lc][ko]);
    aH0 = __builtin_amdgcn_mfma_f32_16x16x32_bf16(a, b0, aH0, 0, 0, 0);
    aH1 = __builtin_amdgcn_mfma_f32_16x16x32_bf16(a, b1, aH1, 0, 0, 0);
    aD  = __builtin_amdgcn_mfma_f32_16x16x32_bf16(a, bd, aD,  0, 0, 0);
  }

  // ---- epilogue in registers: shift corrections + dot*w_dot + input*w_hi[127]
  const float in127  = b2f(st_s[127][128]);
  const float st0127 = b2f(st_s[127][0]);
  const float d127   = dpart[0] + dpart[1];
  const float wd0 = wdot_s[lc], wd1 = wdot_s[lc + 16];
  const float w70 = w127_s[lc], w71 = w127_s[lc + 16];
  float sim0[4], sim1[4];
#pragma unroll
  for (int r = 0; r < 4; ++r) {
    const int row = wv * 16 + lg * 4 + r;
    float st0 = b2f(st_s[row][0]);
    float inr = b2f(st_s[row][128]);
    float dotv = aD[r] - st0 * st0127 + inr * in127;
    if (row == Wx - 1) dotv = d127;                 // exact fp32 diagonal
    sim0[r] = aH0[r] + dotv * wd0 + inr * w70;
    sim1[r] = aH1[r] + dotv * wd1 + inr * w71;
  }

  // ---- softmax over j: per-wave in-register reduce + [8][32] cross-wave LDS
  float m0 = -3.4e38f, m1 = -3.4e38f;
#pragma unroll
  for (int r = 0; r < 4; ++r) { m0 = fmaxf(m0, sim0[r]); m1 = fmaxf(m1, sim1[r]); }
  m0 = fmaxf(m0, __shfl_xor(m0, 16)); m0 = fmaxf(m0, __shfl_xor(m0, 32));
  m1 = fmaxf(m1, __shfl_xor(m1, 16)); m1 = fmaxf(m1, __shfl_xor(m1, 32));
  if (l < 16) { colmax[wv][l] = m0; colmax[wv][16 + l] = m1; }
  __syncthreads();
  float M0 = colmax[0][lc], M1 = colmax[0][lc + 16];
#pragma unroll
  for (int r = 1; r < 8; ++r) {
    M0 = fmaxf(M0, colmax[r][lc]);
    M1 = fmaxf(M1, colmax[r][lc + 16]);
  }
  float s0 = 0.f, s1 = 0.f, p0 = 0.f, p1 = 0.f;
#pragma unroll
  for (int r = 0; r < 4; ++r) {
    const int row = wv * 16 + lg * 4 + r;
    float e0 = __expf(sim0[r] - M0);
    float e1 = __expf(sim1[r] - M1);
    s0 += e0; s1 += e1;
    p0 = fmaf(b2f(st_s[row][vb + lc + 1]), e0, p0);    // flip[row][vb+lc]
    p1 = fmaf(b2f(st_s[row][vb + lc + 17]), e1, p1);   // flip[row][vb+lc+16] ([128]=input)
  }
  s0 += __shfl_xor(s0, 16); s0 += __shfl_xor(s0, 32);
  s1 += __shfl_xor(s1, 16); s1 += __shfl_xor(s1, 32);
  p0 += __shfl_xor(p0, 16); p0 += __shfl_xor(p0, 32);
  p1 += __shfl_xor(p1, 16); p1 += __shfl_xor(p1, 32);
  if (l < 16) {
    colsum[wv][l] = s0; colsum[wv][16 + l] = s1;
    ppart[wv][l]  = p0; ppart[wv][16 + l]  = p1;
  }
  __syncthreads();

  if (wv == 0 && l < VC) {
    float S = 0.f, P = 0.f;
#pragma unroll
    for (int r = 0; r < 8; ++r) { S += colsum[r][l]; P += ppart[r][l]; }
    out[(size_t)b * Ux + vb + l] = P / S;
  }
}

extern "C" void kernel_launch(void* const* d_in, const int* in_sizes, int n_in,
                              void* d_out, int out_size, void* d_ws, size_t ws_size,
                              hipStream_t stream) {
  const float* input = (const float*)d_in[0];
  const float* state = (const float*)d_in[1];
  const float* w     = (const float*)d_in[2];
  // d_in[3] (bias) not needed: cancels in softmax over j.
  float* out = (float*)d_out;
  dim3 grid(NS, Bx);
  rsa_kernel<<<grid, dim3(512), 0, stream>>>(input, state, w, out);
}

// Round 7
// 65.440 us; speedup vs baseline: 1.0673x; 1.0098x over previous
//
#include <hip/hip_runtime.h>
#include <hip/hip_bf16.h>

// RSA layer, B=64, U=W=128. Grid 4x64 (256 blocks = 1/CU), 512 threads (8 waves).
// Only i=W-1 output row needed; hj-term and bias cancel in softmax over j.
// sim-hi matmul + dot matvec via bf16 MFMA 16x16x32; softmax with per-wave
// online (m,s,p) triples + ONE cross-wave exchange (2 barriers total).
constexpr int Bx = 64, Ux = 128, Wx = 128;
constexpr int NS = 4;           // v-chunks per batch
constexpr int VC = 32;          // v columns per block
constexpr int LDST = 136;       // st_s stride (bf16): 272B = 17*16B (b128-aligned rows)
constexpr int LDWT = 136;

typedef __attribute__((ext_vector_type(8))) short s16x8;   // MFMA A/B frag
typedef __attribute__((ext_vector_type(4))) float fx4;     // MFMA C/D frag

static __device__ __forceinline__ short f2b(float x) {     // f32 -> bf16 RNE (cvt_pk-able)
  __hip_bfloat16 h = __float2bfloat16(x);
  return *reinterpret_cast<short*>(&h);
}
static __device__ __forceinline__ float b2f(short s) {     // bf16 -> f32 exact
  union { unsigned u; float f; } c; c.u = ((unsigned)(unsigned short)s) << 16;
  return c.f;
}

__global__ __launch_bounds__(512) void rsa_kernel(const float* __restrict__ input,
                                                  const float* __restrict__ state,
                                                  const float* __restrict__ w,
                                                  float* __restrict__ out) {
  __shared__ __align__(16) short st_s[Wx][LDST];  // [j][k]=state[j][k], [j][128]=input[j]
  __shared__ __align__(16) short wst[VC][LDWT];   // [v][k]=w_hi[k-1][vb+v], [v][0]=0
  __shared__ float wm[8][VC], wsum[8][VC], wp[8][VC];  // per-wave (m,s,p) triples
  __shared__ float w127_s[VC], wdot_s[VC];
  __shared__ float dpart[2];

  const int t = threadIdx.x;
  const int s = blockIdx.x, b = blockIdx.y;
  const int vb = s * VC;
  const float* stb = state + (size_t)b * Ux * Wx;
  const float* inb = input + (size_t)b * Ux;

  // ---- stage state -> bf16 (float4 loads, aligned b128 LDS writes)
#pragma unroll
  for (int i = 0; i < 2; ++i) {
    int g = i * 8192 + t * 16;          // flat f32 index, 16-aligned
    int j = g >> 7, k = g & 127;
    const float4* src = reinterpret_cast<const float4*>(stb + g);
    float4 x0 = src[0], x1 = src[1], x2 = src[2], x3 = src[3];
    s16x8 p0 = { f2b(x0.x), f2b(x0.y), f2b(x0.z), f2b(x0.w),
                 f2b(x1.x), f2b(x1.y), f2b(x1.z), f2b(x1.w) };
    s16x8 p1 = { f2b(x2.x), f2b(x2.y), f2b(x2.z), f2b(x2.w),
                 f2b(x3.x), f2b(x3.y), f2b(x3.z), f2b(x3.w) };
    *reinterpret_cast<s16x8*>(&st_s[j][k])     = p0;
    *reinterpret_cast<s16x8*>(&st_s[j][k + 8]) = p1;
  }
  if (t < Wx) st_s[t][128] = f2b(inb[t]);
  // ---- stage w_hi chunk shifted: wst[v][r+1] = w_hi[r][vb+v], r=0..126
  for (int idx = t; idx < 127 * VC; idx += 512) {
    int r = idx >> 5, v = idx & (VC - 1);
    wst[v][r + 1] = f2b(w[r * Ux + vb + v]);
  }
  if (t < VC) { wst[t][0] = 0; w127_s[t] = w[127 * Ux + vb + t]; }
  else if (t < 2 * VC) wdot_s[t - VC] = w[2 * Ux * Ux + vb + (t - VC)];
  // ---- exact fp32 dot[127] = ||flip_127||^2 (waves 0,1)
  if (t < Wx) {
    float x = (t < Wx - 1) ? stb[127 * Wx + t + 1] : inb[127];
    float p = x * x;
#pragma unroll
    for (int off = 32; off; off >>= 1) p += __shfl_down(p, off);
    if ((t & 63) == 0) dpart[t >> 6] = p;
  }
  __syncthreads();

  // ---- MFMA: wave wv owns j-tile rows wv*16..wv*16+15; 2 v-tiles + dot matvec.
  // A/B frag: row/col = l&15, k-contig 8 at (l>>4)*8; D: col=l&15, row=(l>>4)*4+r
  const int wv = t >> 6, l = t & 63, lc = l & 15, lg = l >> 4;
  fx4 aH0 = {}, aH1 = {}, aD = {};
#pragma unroll
  for (int kt = 0; kt < 4; ++kt) {
    const int ko = kt * 32 + lg * 8;
    s16x8 bd = *reinterpret_cast<const s16x8*>(&st_s[127][ko]);   // broadcast row 127
    s16x8 b0 = *reinterpret_cast<const s16x8*>(&wst[lc][ko]);
    s16x8 b1 = *reinterpret_cast<const s16x8*>(&wst[lc + 16][ko]);
    s16x8 a  = *reinterpret_cast<const s16x8*>(&st_s[wv * 16 + lc][ko]);
    aH0 = __builtin_amdgcn_mfma_f32_16x16x32_bf16(a, b0, aH0, 0, 0, 0);
    aH1 = __builtin_amdgcn_mfma_f32_16x16x32_bf16(a, b1, aH1, 0, 0, 0);
    aD  = __builtin_amdgcn_mfma_f32_16x16x32_bf16(a, bd, aD,  0, 0, 0);
  }

  // ---- epilogue in registers: shift corrections + dot*w_dot + input*w_hi[127]
  const float in127  = b2f(st_s[127][128]);
  const float st0127 = b2f(st_s[127][0]);
  const float d127   = dpart[0] + dpart[1];
  const float wd0 = wdot_s[lc], wd1 = wdot_s[lc + 16];
  const float w70 = w127_s[lc], w71 = w127_s[lc + 16];
  float sim0[4], sim1[4];
#pragma unroll
  for (int r = 0; r < 4; ++r) {
    const int row = wv * 16 + lg * 4 + r;
    float st0 = b2f(st_s[row][0]);
    float inr = b2f(st_s[row][128]);
    float dotv = aD[r] - st0 * st0127 + inr * in127;
    if (row == Wx - 1) dotv = d127;                 // exact fp32 diagonal
    sim0[r] = aH0[r] + dotv * wd0 + inr * w70;
    sim1[r] = aH1[r] + dotv * wd1 + inr * w71;
  }

  // ---- per-wave online softmax: local max m, local sum s, local weighted p
  float m0 = -3.4e38f, m1 = -3.4e38f;
#pragma unroll
  for (int r = 0; r < 4; ++r) { m0 = fmaxf(m0, sim0[r]); m1 = fmaxf(m1, sim1[r]); }
  m0 = fmaxf(m0, __shfl_xor(m0, 16)); m0 = fmaxf(m0, __shfl_xor(m0, 32));
  m1 = fmaxf(m1, __shfl_xor(m1, 16)); m1 = fmaxf(m1, __shfl_xor(m1, 32));
  float s0 = 0.f, s1 = 0.f, p0 = 0.f, p1 = 0.f;
#pragma unroll
  for (int r = 0; r < 4; ++r) {
    const int row = wv * 16 + lg * 4 + r;
    float e0 = __expf(sim0[r] - m0);
    float e1 = __expf(sim1[r] - m1);
    s0 += e0; s1 += e1;
    p0 = fmaf(b2f(st_s[row][vb + lc + 1]), e0, p0);    // flip[row][vb+lc]
    p1 = fmaf(b2f(st_s[row][vb + lc + 17]), e1, p1);   // flip[row][vb+lc+16] ([128]=input)
  }
  s0 += __shfl_xor(s0, 16); s0 += __shfl_xor(s0, 32);
  s1 += __shfl_xor(s1, 16); s1 += __shfl_xor(s1, 32);
  p0 += __shfl_xor(p0, 16); p0 += __shfl_xor(p0, 32);
  p1 += __shfl_xor(p1, 16); p1 += __shfl_xor(p1, 32);
  if (l < 16) {
    wm[wv][l] = m0;  wm[wv][16 + l] = m1;
    wsum[wv][l] = s0; wsum[wv][16 + l] = s1;
    wp[wv][l] = p0;  wp[wv][16 + l] = p1;
  }
  __syncthreads();

  // ---- ONE combine: wave 0 lanes 0..31, rescale partials by e^{m_wv - M}
  if (wv == 0 && l < VC) {
    float M = wm[0][l];
#pragma unroll
    for (int r = 1; r < 8; ++r) M = fmaxf(M, wm[r][l]);
    float S = 0.f, P = 0.f;
#pragma unroll
    for (int r = 0; r < 8; ++r) {
      float sc = __expf(wm[r][l] - M);
      S = fmaf(wsum[r][l], sc, S);
      P = fmaf(wp[r][l],  sc, P);
    }
    out[(size_t)b * Ux + vb + l] = P / S;
  }
}

extern "C" void kernel_launch(void* const* d_in, const int* in_sizes, int n_in,
                              void* d_out, int out_size, void* d_ws, size_t ws_size,
                              hipStream_t stream) {
  const float* input = (const float*)d_in[0];
  const float* state = (const float*)d_in[1];
  const float* w     = (const float*)d_in[2];
  // d_in[3] (bias) not needed: cancels in softmax over j.
  float* out = (float*)d_out;
  dim3 grid(NS, Bx);
  rsa_kernel<<<grid, dim3(512), 0, stream>>>(input, state, w, out);
}